// Round 1
// baseline (839.835 us; speedup 1.0000x reference)
//
#include <hip/hip_runtime.h>

typedef unsigned int u32;

static inline size_t al16(size_t x){ return (x + 15) & ~(size_t)15; }

// Pass 1 over edges: weighted degree (for symmetric norm) + incoming-edge counts (for CSR).
__global__ void k_edge_deg(const int* __restrict__ col, const float* __restrict__ ew,
                           float* __restrict__ deg, u32* __restrict__ cnt, int E) {
  int e = blockIdx.x * blockDim.x + threadIdx.x;
  if (e >= E) return;
  int c = col[e];
  atomicAdd(&deg[c], ew[e]);
  atomicAdd(&cnt[c], 1u);
}

// deg -> dinv in place. Self-loop weight 1 added here (PyG add_self_loops).
__global__ void k_dinv(float* deg, int n) {
  int i = blockIdx.x * blockDim.x + threadIdx.x;
  if (i >= n) return;
  deg[i] = rsqrtf(deg[i] + 1.0f);
}

// Hierarchical exclusive scan of cnt -> rowptr. 2048 elems per block.
__global__ void k_scan1(const u32* __restrict__ cnt, u32* __restrict__ rowptr,
                        u32* __restrict__ bsums, int n) {
  __shared__ u32 s[256];
  int tid = threadIdx.x;
  int base = blockIdx.x * 2048 + tid * 8;
  u32 v[8]; u32 tsum = 0;
  #pragma unroll
  for (int i = 0; i < 8; i++) { int idx = base + i; v[i] = (idx < n) ? cnt[idx] : 0u; tsum += v[i]; }
  s[tid] = tsum; __syncthreads();
  for (int off = 1; off < 256; off <<= 1) {
    u32 t = (tid >= off) ? s[tid - off] : 0u;
    __syncthreads();
    s[tid] += t;
    __syncthreads();
  }
  u32 excl = s[tid] - tsum;
  if (tid == 255) bsums[blockIdx.x] = s[255];
  u32 run = excl;
  #pragma unroll
  for (int i = 0; i < 8; i++) { int idx = base + i; if (idx < n) rowptr[idx] = run; run += v[i]; }
}

__global__ void k_scan2(u32* bsums, u32* rowptr, int nblk, int n) {
  if (threadIdx.x == 0 && blockIdx.x == 0) {
    u32 a = 0;
    for (int b = 0; b < nblk; b++) { u32 t = bsums[b]; bsums[b] = a; a += t; }
    rowptr[n] = a;  // total == E
  }
}

__global__ void k_scan3(u32* __restrict__ rowptr, u32* __restrict__ cursor,
                        const u32* __restrict__ bsums, int n) {
  int i = blockIdx.x * blockDim.x + threadIdx.x;
  if (i >= n) return;
  u32 v = rowptr[i] + bsums[i >> 11];
  rowptr[i] = v;
  cursor[i] = v;
}

// Scatter edges into CSR order; precompute per-edge norm = dinv[src]*w*dinv[dst].
__global__ void k_fill(const int* __restrict__ row, const int* __restrict__ col,
                       const float* __restrict__ ew, const float* __restrict__ dinv,
                       u32* __restrict__ cursor, u32* __restrict__ csr_src,
                       float* __restrict__ csr_nrm, int E) {
  int e = blockIdx.x * blockDim.x + threadIdx.x;
  if (e >= E) return;
  int r = row[e], c = col[e];
  u32 pos = atomicAdd(&cursor[c], 1u);
  csr_src[pos] = (u32)r;
  csr_nrm[pos] = dinv[r] * ew[e] * dinv[c];
}

// ht1 = x @ W1  (100000x128 @ 128x16). W1 staged in LDS, broadcast reads.
__global__ void k_gemm1(const float* __restrict__ x, const float* __restrict__ W1,
                        float* __restrict__ ht1, int n) {
  __shared__ float sw[2048];
  for (int i = threadIdx.x; i < 2048; i += blockDim.x) sw[i] = W1[i];
  __syncthreads();
  int node = blockIdx.x * blockDim.x + threadIdx.x;
  if (node >= n) return;
  const float4* xr = (const float4*)(x + (size_t)node * 128);
  float acc[16];
  #pragma unroll
  for (int j = 0; j < 16; j++) acc[j] = 0.f;
  #pragma unroll 4
  for (int k4 = 0; k4 < 32; k4++) {
    float4 xv = xr[k4];
    const float* wb = &sw[k4 * 64];
    #pragma unroll
    for (int j = 0; j < 16; j++) acc[j] += xv.x * wb[j];
    #pragma unroll
    for (int j = 0; j < 16; j++) acc[j] += xv.y * wb[16 + j];
    #pragma unroll
    for (int j = 0; j < 16; j++) acc[j] += xv.z * wb[32 + j];
    #pragma unroll
    for (int j = 0; j < 16; j++) acc[j] += xv.w * wb[48 + j];
  }
  float4* o = (float4*)(ht1 + (size_t)node * 16);
  o[0] = make_float4(acc[0], acc[1], acc[2], acc[3]);
  o[1] = make_float4(acc[4], acc[5], acc[6], acc[7]);
  o[2] = make_float4(acc[8], acc[9], acc[10], acc[11]);
  o[3] = make_float4(acc[12], acc[13], acc[14], acc[15]);
}

// Conv1 aggregation + bias + relu, fused with @W2 via LDS (writes conv2's pre-agg h).
// 16 lanes per node, lane = channel.
__global__ void k_agg1(const float* __restrict__ ht1, const u32* __restrict__ rowptr,
                       const u32* __restrict__ csr_src, const float* __restrict__ csr_nrm,
                       const float* __restrict__ dinv, const float* __restrict__ b1,
                       const float* __restrict__ W2, float* __restrict__ ht2, int n) {
  __shared__ float sw2[256];
  __shared__ float sr[16][17];
  int tid = threadIdx.x;
  sw2[tid] = W2[tid];
  int g = tid >> 4, j = tid & 15;
  int node = blockIdx.x * 16 + g;
  float acc = 0.f;
  if (node < n) {
    u32 e0 = rowptr[node], e1 = rowptr[node + 1];
    for (u32 e = e0; e < e1; e++) {
      acc += csr_nrm[e] * ht1[(size_t)csr_src[e] * 16 + j];
    }
    float di = dinv[node];
    acc += di * di * ht1[(size_t)node * 16 + j];
    acc += b1[j];
    acc = fmaxf(acc, 0.f);
  }
  sr[g][j] = acc;
  __syncthreads();
  if (node < n) {
    float s = 0.f;
    #pragma unroll
    for (int k = 0; k < 16; k++) s += sr[g][k] * sw2[k * 16 + j];
    ht2[(size_t)node * 16 + j] = s;
  }
}

// Conv2 aggregation + bias, fused with mean-pool partial sums (atomic into pooled).
__global__ void k_agg2(const float* __restrict__ ht2, const u32* __restrict__ rowptr,
                       const u32* __restrict__ csr_src, const float* __restrict__ csr_nrm,
                       const float* __restrict__ dinv, const float* __restrict__ b2,
                       const int* __restrict__ batch, float* __restrict__ pooled, int n) {
  int tid = threadIdx.x;
  int g = tid >> 4, j = tid & 15;
  int node = blockIdx.x * 16 + g;
  if (node >= n) return;
  float acc = 0.f;
  u32 e0 = rowptr[node], e1 = rowptr[node + 1];
  for (u32 e = e0; e < e1; e++) acc += csr_nrm[e] * ht2[(size_t)csr_src[e] * 16 + j];
  float di = dinv[node];
  acc += di * di * ht2[(size_t)node * 16 + j];
  acc += b2[j];
  atomicAdd(&pooled[(size_t)batch[node] * 16 + j], acc);
}

// Mean + FC. Graph sizes via binary search on sorted batch (no histogram pass).
__global__ void k_final(const float* __restrict__ pooled, const int* __restrict__ batch,
                        const float* __restrict__ fcW, const float* __restrict__ fcb,
                        float* __restrict__ out, int n, int G) {
  int g = blockIdx.x * blockDim.x + threadIdx.x;
  if (g >= G) return;
  int lo = 0, hi = n;
  while (lo < hi) { int m = (lo + hi) >> 1; if (batch[m] < g) lo = m + 1; else hi = m; }
  int lo2 = lo, hi2 = n;
  while (lo2 < hi2) { int m = (lo2 + hi2) >> 1; if (batch[m] < g + 1) lo2 = m + 1; else hi2 = m; }
  float c = (float)(lo2 - lo);
  float inv = 1.0f / fmaxf(c, 1.0f);
  float s = 0.f;
  #pragma unroll
  for (int j = 0; j < 16; j++) s += pooled[g * 16 + j] * fcW[j];
  out[g] = s * inv + fcb[0];
}

extern "C" void kernel_launch(void* const* d_in, const int* in_sizes, int n_in,
                              void* d_out, int out_size, void* d_ws, size_t ws_size,
                              hipStream_t stream) {
  const float* x    = (const float*)d_in[0];
  const int*   ei   = (const int*)d_in[1];
  const float* ew   = (const float*)d_in[2];
  const int*   batch= (const int*)d_in[3];
  const float* W1   = (const float*)d_in[4];
  const float* b1   = (const float*)d_in[5];
  const float* W2   = (const float*)d_in[6];
  const float* b2   = (const float*)d_in[7];
  const float* fcW  = (const float*)d_in[8];
  const float* fcb  = (const float*)d_in[9];
  float* out = (float*)d_out;

  int N = in_sizes[3];
  int E = in_sizes[2];
  int G = out_size;        // OUT = 1 per graph
  const int* row = ei;     // edge_index[0] = source
  const int* col = ei + E; // edge_index[1] = target

  char* w = (char*)d_ws;
  size_t off = 0;
  auto alloc = [&](size_t bytes) -> char* { char* p = w + off; off = al16(off + bytes); return p; };
  float* deg    = (float*)alloc((size_t)N * 4);        // becomes dinv in-place
  u32*   cnt    = (u32*)  alloc((size_t)N * 4);
  u32*   rowptr = (u32*)  alloc(((size_t)N + 1) * 4);
  u32*   cursor = (u32*)  alloc((size_t)N * 4);
  u32*   bsums  = (u32*)  alloc(64 * 4);
  u32*   csr_src= (u32*)  alloc((size_t)E * 4);
  float* csr_nrm= (float*)alloc((size_t)E * 4);
  float* ht1    = (float*)alloc((size_t)N * 16 * 4);
  float* ht2    = (float*)alloc((size_t)N * 16 * 4);
  float* pooled = (float*)alloc((size_t)G * 16 * 4);
  (void)ws_size; (void)n_in;

  hipMemsetAsync(deg, 0, (size_t)N * 4, stream);
  hipMemsetAsync(cnt, 0, (size_t)N * 4, stream);
  hipMemsetAsync(pooled, 0, (size_t)G * 16 * 4, stream);

  int eb = (E + 255) / 256;
  int nb = (N + 255) / 256;
  int sb = (N + 2047) / 2048;
  int ab = (N + 15) / 16;
  int gb = (G + 255) / 256;

  k_edge_deg<<<eb, 256, 0, stream>>>(col, ew, deg, cnt, E);
  k_dinv<<<nb, 256, 0, stream>>>(deg, N);
  k_scan1<<<sb, 256, 0, stream>>>(cnt, rowptr, bsums, N);
  k_scan2<<<1, 64, 0, stream>>>(bsums, rowptr, sb, N);
  k_scan3<<<nb, 256, 0, stream>>>(rowptr, cursor, bsums, N);
  k_fill<<<eb, 256, 0, stream>>>(row, col, ew, deg, cursor, csr_src, csr_nrm, E);
  k_gemm1<<<nb, 256, 0, stream>>>(x, W1, ht1, N);
  k_agg1<<<ab, 256, 0, stream>>>(ht1, rowptr, csr_src, csr_nrm, deg, b1, W2, ht2, N);
  k_agg2<<<ab, 256, 0, stream>>>(ht2, rowptr, csr_src, csr_nrm, deg, b2, batch, pooled, N);
  k_final<<<gb, 256, 0, stream>>>(pooled, batch, fcW, fcb, out, N, G);
}

// Round 2
// 488.306 us; speedup vs baseline: 1.7199x; 1.7199x over previous
//
#include <hip/hip_runtime.h>

typedef unsigned int u32;

static inline size_t al16(size_t x){ return (x + 15) & ~(size_t)15; }

// Pass 1: per-edge local offset via count atomic (one u32 atomic per edge, value reused as cursor).
__global__ void k_count(const int* __restrict__ col, u32* __restrict__ cnt,
                        u32* __restrict__ lofs, int E) {
  int e = blockIdx.x * blockDim.x + threadIdx.x;
  if (e >= E) return;
  lofs[e] = atomicAdd(&cnt[col[e]], 1u);
}

// Hierarchical exclusive scan of cnt -> rowptr. 2048 elems per block.
__global__ void k_scan1(const u32* __restrict__ cnt, u32* __restrict__ rowptr,
                        u32* __restrict__ bsums, int n) {
  __shared__ u32 s[256];
  int tid = threadIdx.x;
  int base = blockIdx.x * 2048 + tid * 8;
  u32 v[8]; u32 tsum = 0;
  #pragma unroll
  for (int i = 0; i < 8; i++) { int idx = base + i; v[i] = (idx < n) ? cnt[idx] : 0u; tsum += v[i]; }
  s[tid] = tsum; __syncthreads();
  for (int off = 1; off < 256; off <<= 1) {
    u32 t = (tid >= off) ? s[tid - off] : 0u;
    __syncthreads();
    s[tid] += t;
    __syncthreads();
  }
  u32 excl = s[tid] - tsum;
  if (tid == 255) bsums[blockIdx.x] = s[255];
  u32 run = excl;
  #pragma unroll
  for (int i = 0; i < 8; i++) { int idx = base + i; if (idx < n) rowptr[idx] = run; run += v[i]; }
}

__global__ void k_scan2(u32* bsums, u32* rowptr, int nblk, int n) {
  if (threadIdx.x == 0 && blockIdx.x == 0) {
    u32 a = 0;
    for (int b = 0; b < nblk; b++) { u32 t = bsums[b]; bsums[b] = a; a += t; }
    rowptr[n] = a;  // total == E
  }
}

__global__ void k_scan3(u32* __restrict__ rowptr, const u32* __restrict__ bsums, int n) {
  int i = blockIdx.x * blockDim.x + threadIdx.x;
  if (i >= n) return;
  rowptr[i] += bsums[i >> 11];
}

// Scatter edges into CSR order (atomic-free: slot = rowptr[dst] + lofs[e]).
// One packed 8B store per edge: {src, bits(w)}.
__global__ void k_fill(const int* __restrict__ row, const int* __restrict__ col,
                       const float* __restrict__ ew, const u32* __restrict__ rowptr,
                       const u32* __restrict__ lofs, uint2* __restrict__ csr, int E) {
  int e = blockIdx.x * blockDim.x + threadIdx.x;
  if (e >= E) return;
  u32 pos = rowptr[col[e]] + lofs[e];
  uint2 v; v.x = (u32)row[e]; v.y = __float_as_uint(ew[e]);
  csr[pos] = v;
}

// Weighted in-degree from CSR (sequential reads, no atomics) -> dinv.
// 16 lanes per node, shuffle-reduce.
__global__ void k_deg(const uint2* __restrict__ csr, const u32* __restrict__ rowptr,
                      float* __restrict__ dinv, int n) {
  int tid = threadIdx.x;
  int g = tid >> 4, j = tid & 15;
  int node = blockIdx.x * 16 + g;
  if (node >= n) return;
  u32 e0 = rowptr[node], e1 = rowptr[node + 1];
  float s = 0.f;
  for (u32 e = e0 + j; e < e1; e += 16) s += __uint_as_float(csr[e].y);
  #pragma unroll
  for (int off = 8; off; off >>= 1) s += __shfl_down(s, off, 16);
  if (j == 0) dinv[node] = rsqrtf(s + 1.0f);  // +1 = self-loop weight
}

// ht1 = x @ W1  (100000x128 @ 128x16). W1 staged in LDS, broadcast reads.
__global__ void k_gemm1(const float* __restrict__ x, const float* __restrict__ W1,
                        float* __restrict__ ht1, int n) {
  __shared__ float sw[2048];
  for (int i = threadIdx.x; i < 2048; i += blockDim.x) sw[i] = W1[i];
  __syncthreads();
  int node = blockIdx.x * blockDim.x + threadIdx.x;
  if (node >= n) return;
  const float4* xr = (const float4*)(x + (size_t)node * 128);
  float acc[16];
  #pragma unroll
  for (int j = 0; j < 16; j++) acc[j] = 0.f;
  #pragma unroll 4
  for (int k4 = 0; k4 < 32; k4++) {
    float4 xv = xr[k4];
    const float* wb = &sw[k4 * 64];
    #pragma unroll
    for (int j = 0; j < 16; j++) acc[j] += xv.x * wb[j];
    #pragma unroll
    for (int j = 0; j < 16; j++) acc[j] += xv.y * wb[16 + j];
    #pragma unroll
    for (int j = 0; j < 16; j++) acc[j] += xv.z * wb[32 + j];
    #pragma unroll
    for (int j = 0; j < 16; j++) acc[j] += xv.w * wb[48 + j];
  }
  float4* o = (float4*)(ht1 + (size_t)node * 16);
  o[0] = make_float4(acc[0], acc[1], acc[2], acc[3]);
  o[1] = make_float4(acc[4], acc[5], acc[6], acc[7]);
  o[2] = make_float4(acc[8], acc[9], acc[10], acc[11]);
  o[3] = make_float4(acc[12], acc[13], acc[14], acc[15]);
}

// Conv1 aggregation + bias + relu, fused with @W2 via LDS (writes conv2's pre-agg h).
// 16 lanes per node, lane = channel. norm computed on the fly from dinv (L2-resident).
__global__ void k_agg1(const float* __restrict__ ht1, const u32* __restrict__ rowptr,
                       const uint2* __restrict__ csr, const float* __restrict__ dinv,
                       const float* __restrict__ b1, const float* __restrict__ W2,
                       float* __restrict__ ht2, int n) {
  __shared__ float sw2[256];
  __shared__ float sr[16][17];
  int tid = threadIdx.x;
  sw2[tid] = W2[tid];
  int g = tid >> 4, j = tid & 15;
  int node = blockIdx.x * 16 + g;
  float acc = 0.f;
  if (node < n) {
    float di = dinv[node];
    u32 e0 = rowptr[node], e1 = rowptr[node + 1];
    for (u32 e = e0; e < e1; e++) {
      uint2 v = csr[e];                     // broadcast 8B across the 16 lanes
      float nrm = dinv[v.x] * __uint_as_float(v.y) * di;
      acc += nrm * ht1[(size_t)v.x * 16 + j];
    }
    acc += di * di * ht1[(size_t)node * 16 + j];
    acc += b1[j];
    acc = fmaxf(acc, 0.f);
  }
  sr[g][j] = acc;
  __syncthreads();
  if (node < n) {
    float s = 0.f;
    #pragma unroll
    for (int k = 0; k < 16; k++) s += sr[g][k] * sw2[k * 16 + j];
    ht2[(size_t)node * 16 + j] = s;
  }
}

// Conv2 aggregation + bias, fused with mean-pool partial sums (atomic into pooled).
__global__ void k_agg2(const float* __restrict__ ht2, const u32* __restrict__ rowptr,
                       const uint2* __restrict__ csr, const float* __restrict__ dinv,
                       const float* __restrict__ b2, const int* __restrict__ batch,
                       float* __restrict__ pooled, int n) {
  int tid = threadIdx.x;
  int g = tid >> 4, j = tid & 15;
  int node = blockIdx.x * 16 + g;
  if (node >= n) return;
  float di = dinv[node];
  float acc = 0.f;
  u32 e0 = rowptr[node], e1 = rowptr[node + 1];
  for (u32 e = e0; e < e1; e++) {
    uint2 v = csr[e];
    float nrm = dinv[v.x] * __uint_as_float(v.y) * di;
    acc += nrm * ht2[(size_t)v.x * 16 + j];
  }
  acc += di * di * ht2[(size_t)node * 16 + j];
  acc += b2[j];
  atomicAdd(&pooled[(size_t)batch[node] * 16 + j], acc);
}

// Mean + FC. Graph sizes via binary search on sorted batch (no histogram pass).
__global__ void k_final(const float* __restrict__ pooled, const int* __restrict__ batch,
                        const float* __restrict__ fcW, const float* __restrict__ fcb,
                        float* __restrict__ out, int n, int G) {
  int g = blockIdx.x * blockDim.x + threadIdx.x;
  if (g >= G) return;
  int lo = 0, hi = n;
  while (lo < hi) { int m = (lo + hi) >> 1; if (batch[m] < g) lo = m + 1; else hi = m; }
  int lo2 = lo, hi2 = n;
  while (lo2 < hi2) { int m = (lo2 + hi2) >> 1; if (batch[m] < g + 1) lo2 = m + 1; else hi2 = m; }
  float c = (float)(lo2 - lo);
  float inv = 1.0f / fmaxf(c, 1.0f);
  float s = 0.f;
  #pragma unroll
  for (int j = 0; j < 16; j++) s += pooled[g * 16 + j] * fcW[j];
  out[g] = s * inv + fcb[0];
}

extern "C" void kernel_launch(void* const* d_in, const int* in_sizes, int n_in,
                              void* d_out, int out_size, void* d_ws, size_t ws_size,
                              hipStream_t stream) {
  const float* x    = (const float*)d_in[0];
  const int*   ei   = (const int*)d_in[1];
  const float* ew   = (const float*)d_in[2];
  const int*   batch= (const int*)d_in[3];
  const float* W1   = (const float*)d_in[4];
  const float* b1   = (const float*)d_in[5];
  const float* W2   = (const float*)d_in[6];
  const float* b2   = (const float*)d_in[7];
  const float* fcW  = (const float*)d_in[8];
  const float* fcb  = (const float*)d_in[9];
  float* out = (float*)d_out;

  int N = in_sizes[3];
  int E = in_sizes[2];
  int G = out_size;        // OUT = 1 per graph
  const int* row = ei;     // edge_index[0] = source
  const int* col = ei + E; // edge_index[1] = target

  char* w = (char*)d_ws;
  size_t off = 0;
  auto alloc = [&](size_t bytes) -> char* { char* p = w + off; off = al16(off + bytes); return p; };
  u32*   cnt    = (u32*)  alloc((size_t)N * 4);
  u32*   rowptr = (u32*)  alloc(((size_t)N + 1) * 4);
  u32*   bsums  = (u32*)  alloc(64 * 4);
  u32*   lofs   = (u32*)  alloc((size_t)E * 4);
  uint2* csr    = (uint2*)alloc((size_t)E * 8);
  float* dinv   = (float*)alloc((size_t)N * 4);
  float* ht1    = (float*)alloc((size_t)N * 16 * 4);
  float* ht2    = (float*)alloc((size_t)N * 16 * 4);
  float* pooled = (float*)alloc((size_t)G * 16 * 4);
  (void)ws_size; (void)n_in;

  hipMemsetAsync(cnt, 0, (size_t)N * 4, stream);
  hipMemsetAsync(pooled, 0, (size_t)G * 16 * 4, stream);

  int eb = (E + 255) / 256;
  int nb = (N + 255) / 256;
  int sb = (N + 2047) / 2048;
  int ab = (N + 15) / 16;
  int gb = (G + 255) / 256;

  k_count<<<eb, 256, 0, stream>>>(col, cnt, lofs, E);
  k_scan1<<<sb, 256, 0, stream>>>(cnt, rowptr, bsums, N);
  k_scan2<<<1, 64, 0, stream>>>(bsums, rowptr, sb, N);
  k_scan3<<<nb, 256, 0, stream>>>(rowptr, bsums, N);
  k_fill<<<eb, 256, 0, stream>>>(row, col, ew, rowptr, lofs, csr, E);
  k_deg<<<ab, 256, 0, stream>>>(csr, rowptr, dinv, N);
  k_gemm1<<<nb, 256, 0, stream>>>(x, W1, ht1, N);
  k_agg1<<<ab, 256, 0, stream>>>(ht1, rowptr, csr, dinv, b1, W2, ht2, N);
  k_agg2<<<ab, 256, 0, stream>>>(ht2, rowptr, csr, dinv, b2, batch, pooled, N);
  k_final<<<gb, 256, 0, stream>>>(pooled, batch, fcW, fcb, out, N, G);
}

// Round 3
// 368.917 us; speedup vs baseline: 2.2765x; 1.3236x over previous
//
#include <hip/hip_runtime.h>

typedef unsigned int u32;

static inline size_t al16(size_t x){ return (x + 15) & ~(size_t)15; }

// Pass 1: per-edge local offset via count atomic (one u32 atomic per edge, value reused as cursor).
__global__ void k_count(const int* __restrict__ col, u32* __restrict__ cnt,
                        u32* __restrict__ lofs, int E) {
  int e = blockIdx.x * blockDim.x + threadIdx.x;
  if (e >= E) return;
  lofs[e] = atomicAdd(&cnt[col[e]], 1u);
}

// Hierarchical exclusive scan of cnt -> rowptr. 2048 elems per block.
__global__ void k_scan1(const u32* __restrict__ cnt, u32* __restrict__ rowptr,
                        u32* __restrict__ bsums, int n) {
  __shared__ u32 s[256];
  int tid = threadIdx.x;
  int base = blockIdx.x * 2048 + tid * 8;
  u32 v[8]; u32 tsum = 0;
  #pragma unroll
  for (int i = 0; i < 8; i++) { int idx = base + i; v[i] = (idx < n) ? cnt[idx] : 0u; tsum += v[i]; }
  s[tid] = tsum; __syncthreads();
  for (int off = 1; off < 256; off <<= 1) {
    u32 t = (tid >= off) ? s[tid - off] : 0u;
    __syncthreads();
    s[tid] += t;
    __syncthreads();
  }
  u32 excl = s[tid] - tsum;
  if (tid == 255) bsums[blockIdx.x] = s[255];
  u32 run = excl;
  #pragma unroll
  for (int i = 0; i < 8; i++) { int idx = base + i; if (idx < n) rowptr[idx] = run; run += v[i]; }
}

__global__ void k_scan2(u32* bsums, u32* rowptr, int nblk, int n) {
  if (threadIdx.x == 0 && blockIdx.x == 0) {
    u32 a = 0;
    for (int b = 0; b < nblk; b++) { u32 t = bsums[b]; bsums[b] = a; a += t; }
    rowptr[n] = a;  // total == E
  }
}

__global__ void k_scan3(u32* __restrict__ rowptr, const u32* __restrict__ bsums, int n) {
  int i = blockIdx.x * blockDim.x + threadIdx.x;
  if (i >= n) return;
  rowptr[i] += bsums[i >> 11];
}

// Scatter edges into CSR order (atomic-free: slot = rowptr[dst] + lofs[e]).
__global__ void k_fill(const int* __restrict__ row, const int* __restrict__ col,
                       const float* __restrict__ ew, const u32* __restrict__ rowptr,
                       const u32* __restrict__ lofs, uint2* __restrict__ csr, int E) {
  int e = blockIdx.x * blockDim.x + threadIdx.x;
  if (e >= E) return;
  u32 pos = rowptr[col[e]] + lofs[e];
  uint2 v; v.x = (u32)row[e]; v.y = __float_as_uint(ew[e]);
  csr[pos] = v;
}

// Weighted in-degree from CSR (sequential reads, no atomics) -> dinv.
__global__ void k_deg(const uint2* __restrict__ csr, const u32* __restrict__ rowptr,
                      float* __restrict__ dinv, int n) {
  int tid = threadIdx.x;
  int g = tid >> 4, j = tid & 15;
  int node = blockIdx.x * 16 + g;
  if (node >= n) return;
  u32 e0 = rowptr[node], e1 = rowptr[node + 1];
  float s = 0.f;
  for (u32 e = e0 + j; e < e1; e += 16) s += __uint_as_float(csr[e].y);
  #pragma unroll
  for (int off = 8; off; off >>= 1) s += __shfl_down(s, off, 16);
  if (j == 0) dinv[node] = rsqrtf(s + 1.0f);  // +1 = self-loop weight
}

// ht1 = x @ W1  (100000x128 @ 128x16). W1 staged in LDS, broadcast reads.
__global__ void k_gemm1(const float* __restrict__ x, const float* __restrict__ W1,
                        float* __restrict__ ht1, int n) {
  __shared__ float sw[2048];
  for (int i = threadIdx.x; i < 2048; i += blockDim.x) sw[i] = W1[i];
  __syncthreads();
  int node = blockIdx.x * blockDim.x + threadIdx.x;
  if (node >= n) return;
  const float4* xr = (const float4*)(x + (size_t)node * 128);
  float acc[16];
  #pragma unroll
  for (int j = 0; j < 16; j++) acc[j] = 0.f;
  #pragma unroll 4
  for (int k4 = 0; k4 < 32; k4++) {
    float4 xv = xr[k4];
    const float* wb = &sw[k4 * 64];
    #pragma unroll
    for (int j = 0; j < 16; j++) acc[j] += xv.x * wb[j];
    #pragma unroll
    for (int j = 0; j < 16; j++) acc[j] += xv.y * wb[16 + j];
    #pragma unroll
    for (int j = 0; j < 16; j++) acc[j] += xv.z * wb[32 + j];
    #pragma unroll
    for (int j = 0; j < 16; j++) acc[j] += xv.w * wb[48 + j];
  }
  float4* o = (float4*)(ht1 + (size_t)node * 16);
  o[0] = make_float4(acc[0], acc[1], acc[2], acc[3]);
  o[1] = make_float4(acc[4], acc[5], acc[6], acc[7]);
  o[2] = make_float4(acc[8], acc[9], acc[10], acc[11]);
  o[3] = make_float4(acc[12], acc[13], acc[14], acc[15]);
}

// Edge-sum with 8x unrolled, independent load chains (breaks the serial
// csr->gather dependency: ~2 round trips per 8 edges instead of per edge).
__device__ __forceinline__ float edge_sum(const float* __restrict__ ht,
                                          const uint2* __restrict__ csr,
                                          const float* __restrict__ dinv,
                                          u32 e0, u32 e1, int j) {
  float acc = 0.f;
  u32 e = e0;
  for (; e + 8 <= e1; e += 8) {
    uint2 v[8];
    #pragma unroll
    for (int t = 0; t < 8; t++) v[t] = csr[e + t];
    float h[8];
    #pragma unroll
    for (int t = 0; t < 8; t++) h[t] = ht[(size_t)v[t].x * 16 + j];
    float nw[8];
    #pragma unroll
    for (int t = 0; t < 8; t++) nw[t] = dinv[v[t].x] * __uint_as_float(v[t].y);
    #pragma unroll
    for (int t = 0; t < 8; t++) acc += nw[t] * h[t];
  }
  for (; e < e1; e++) {
    uint2 v = csr[e];
    acc += dinv[v.x] * __uint_as_float(v.y) * ht[(size_t)v.x * 16 + j];
  }
  return acc;
}

// Conv1 aggregation + bias + relu, fused with @W2 via LDS.
__global__ void k_agg1(const float* __restrict__ ht1, const u32* __restrict__ rowptr,
                       const uint2* __restrict__ csr, const float* __restrict__ dinv,
                       const float* __restrict__ b1, const float* __restrict__ W2,
                       float* __restrict__ ht2, int n) {
  __shared__ float sw2[256];
  __shared__ float sr[16][17];
  int tid = threadIdx.x;
  sw2[tid] = W2[tid];
  int g = tid >> 4, j = tid & 15;
  int node = blockIdx.x * 16 + g;
  float acc = 0.f;
  if (node < n) {
    float di = dinv[node];
    u32 e0 = rowptr[node], e1 = rowptr[node + 1];
    acc = edge_sum(ht1, csr, dinv, e0, e1, j);
    acc = di * (acc + di * ht1[(size_t)node * 16 + j]) + b1[j];
    acc = fmaxf(acc, 0.f);
  }
  sr[g][j] = acc;
  __syncthreads();
  if (node < n) {
    float s = 0.f;
    #pragma unroll
    for (int k = 0; k < 16; k++) s += sr[g][k] * sw2[k * 16 + j];
    ht2[(size_t)node * 16 + j] = s;
  }
}

// Conv2 aggregation + bias, fused with mean-pool partial sums.
// Pool atomics reduced via LDS segmented reduction (batch is sorted -> ~1-2
// graphs per 16-node block), then native f32 atomics.
__global__ void k_agg2(const float* __restrict__ ht2, const u32* __restrict__ rowptr,
                       const uint2* __restrict__ csr, const float* __restrict__ dinv,
                       const float* __restrict__ b2, const int* __restrict__ batch,
                       float* __restrict__ pooled, int n) {
  __shared__ float sr[16][17];
  __shared__ int sbid[16];
  int tid = threadIdx.x;
  int g = tid >> 4, j = tid & 15;
  int node = blockIdx.x * 16 + g;
  float acc = 0.f;
  int myb = -1;
  if (node < n) {
    float di = dinv[node];
    u32 e0 = rowptr[node], e1 = rowptr[node + 1];
    acc = edge_sum(ht2, csr, dinv, e0, e1, j);
    acc = di * (acc + di * ht2[(size_t)node * 16 + j]) + b2[j];
    myb = batch[node];
  }
  sr[g][j] = acc;
  if (j == 0) sbid[g] = myb;
  __syncthreads();
  if (node < n) {
    bool head = (g == 0) || (sbid[g - 1] != myb);
    if (head) {
      float s = sr[g][j];
      for (int t = g + 1; t < 16 && sbid[t] == myb; t++) s += sr[t][j];
      unsafeAtomicAdd(&pooled[(size_t)myb * 16 + j], s);
    }
  }
}

// Mean + FC. Graph sizes via binary search on sorted batch.
__global__ void k_final(const float* __restrict__ pooled, const int* __restrict__ batch,
                        const float* __restrict__ fcW, const float* __restrict__ fcb,
                        float* __restrict__ out, int n, int G) {
  int g = blockIdx.x * blockDim.x + threadIdx.x;
  if (g >= G) return;
  int lo = 0, hi = n;
  while (lo < hi) { int m = (lo + hi) >> 1; if (batch[m] < g) lo = m + 1; else hi = m; }
  int lo2 = lo, hi2 = n;
  while (lo2 < hi2) { int m = (lo2 + hi2) >> 1; if (batch[m] < g + 1) lo2 = m + 1; else hi2 = m; }
  float c = (float)(lo2 - lo);
  float inv = 1.0f / fmaxf(c, 1.0f);
  float s = 0.f;
  #pragma unroll
  for (int j = 0; j < 16; j++) s += pooled[g * 16 + j] * fcW[j];
  out[g] = s * inv + fcb[0];
}

extern "C" void kernel_launch(void* const* d_in, const int* in_sizes, int n_in,
                              void* d_out, int out_size, void* d_ws, size_t ws_size,
                              hipStream_t stream) {
  const float* x    = (const float*)d_in[0];
  const int*   ei   = (const int*)d_in[1];
  const float* ew   = (const float*)d_in[2];
  const int*   batch= (const int*)d_in[3];
  const float* W1   = (const float*)d_in[4];
  const float* b1   = (const float*)d_in[5];
  const float* W2   = (const float*)d_in[6];
  const float* b2   = (const float*)d_in[7];
  const float* fcW  = (const float*)d_in[8];
  const float* fcb  = (const float*)d_in[9];
  float* out = (float*)d_out;

  int N = in_sizes[3];
  int E = in_sizes[2];
  int G = out_size;
  const int* row = ei;     // edge_index[0] = source
  const int* col = ei + E; // edge_index[1] = target

  char* w = (char*)d_ws;
  size_t off = 0;
  auto alloc = [&](size_t bytes) -> char* { char* p = w + off; off = al16(off + bytes); return p; };
  u32*   cnt    = (u32*)  alloc((size_t)N * 4);
  u32*   rowptr = (u32*)  alloc(((size_t)N + 1) * 4);
  u32*   bsums  = (u32*)  alloc(64 * 4);
  u32*   lofs   = (u32*)  alloc((size_t)E * 4);
  uint2* csr    = (uint2*)alloc((size_t)E * 8);
  float* dinv   = (float*)alloc((size_t)N * 4);
  float* ht1    = (float*)alloc((size_t)N * 16 * 4);
  float* ht2    = (float*)alloc((size_t)N * 16 * 4);
  float* pooled = (float*)alloc((size_t)G * 16 * 4);
  (void)ws_size; (void)n_in;

  hipMemsetAsync(cnt, 0, (size_t)N * 4, stream);
  hipMemsetAsync(pooled, 0, (size_t)G * 16 * 4, stream);

  int eb = (E + 255) / 256;
  int nb = (N + 255) / 256;
  int sb = (N + 2047) / 2048;
  int ab = (N + 15) / 16;
  int gb = (G + 255) / 256;

  k_count<<<eb, 256, 0, stream>>>(col, cnt, lofs, E);
  k_scan1<<<sb, 256, 0, stream>>>(cnt, rowptr, bsums, N);
  k_scan2<<<1, 64, 0, stream>>>(bsums, rowptr, sb, N);
  k_scan3<<<nb, 256, 0, stream>>>(rowptr, bsums, N);
  k_fill<<<eb, 256, 0, stream>>>(row, col, ew, rowptr, lofs, csr, E);
  k_deg<<<ab, 256, 0, stream>>>(csr, rowptr, dinv, N);
  k_gemm1<<<nb, 256, 0, stream>>>(x, W1, ht1, N);
  k_agg1<<<ab, 256, 0, stream>>>(ht1, rowptr, csr, dinv, b1, W2, ht2, N);
  k_agg2<<<ab, 256, 0, stream>>>(ht2, rowptr, csr, dinv, b2, batch, pooled, N);
  k_final<<<gb, 256, 0, stream>>>(pooled, batch, fcW, fcb, out, N, G);
}

// Round 4
// 277.267 us; speedup vs baseline: 3.0290x; 1.3305x over previous
//
#include <hip/hip_runtime.h>

typedef unsigned int u32;

static inline size_t al16(size_t x){ return (x + 15) & ~(size_t)15; }

#define NBLK_E 256          // blocks for edge-partition phases (hist/part)
#define BSH 8               // 256 nodes per bucket
#define BMSK 255

// Phase A1: per-block LDS histogram of dst buckets. hist layout [bucket*NBLK_E + blk].
__global__ void k_hist(const int* __restrict__ col, u32* __restrict__ hist,
                       int E, int NB, int chunk) {
  __shared__ u32 h[512];
  int tid = threadIdx.x, blk = blockIdx.x;
  for (int i = tid; i < 512; i += 256) h[i] = 0;
  __syncthreads();
  int e0 = blk * chunk, e1 = min(E, e0 + chunk);
  for (int e = e0 + tid; e < e1; e += 256) atomicAdd(&h[col[e] >> BSH], 1u);
  __syncthreads();
  for (int i = tid; i < NB; i += 256) hist[(size_t)i * NBLK_E + blk] = h[i];
}

// Phase A2a: per-bucket exclusive scan over blocks -> hofs; bucket totals.
__global__ void k_cscan(const u32* __restrict__ hist, u32* __restrict__ hofs,
                        u32* __restrict__ totals) {
  __shared__ u32 s[256];
  int i = blockIdx.x, t = threadIdx.x;
  u32 v = hist[(size_t)i * NBLK_E + t];
  s[t] = v; __syncthreads();
  for (int off = 1; off < 256; off <<= 1) {
    u32 x = (t >= off) ? s[t - off] : 0u;
    __syncthreads(); s[t] += x; __syncthreads();
  }
  hofs[(size_t)i * NBLK_E + t] = s[t] - v;
  if (t == 255) totals[i] = s[255];
}

// Phase A2b: scan bucket totals -> bstart (edge-region & CSR base per bucket).
__global__ void k_bscan(const u32* __restrict__ totals, u32* __restrict__ bstart,
                        u32* __restrict__ rowptr, int NB, int N, int E) {
  __shared__ u32 s[512];
  int t = threadIdx.x;
  u32 v = (t < NB) ? totals[t] : 0u;
  s[t] = v; __syncthreads();
  for (int off = 1; off < 512; off <<= 1) {
    u32 x = (t >= off) ? s[t - off] : 0u;
    __syncthreads(); s[t] += x; __syncthreads();
  }
  if (t < NB) bstart[t] = s[t] - v;
  if (t == 0) { bstart[NB] = (u32)E; rowptr[N] = (u32)E; }
}

// Phase A3: scatter edges into bucket-contiguous records. No global atomics:
// base = bstart[b] + hofs[b][blk]; within-block rank via LDS atomic.
__global__ void k_part(const int* __restrict__ row, const int* __restrict__ col,
                       const float* __restrict__ ew, const u32* __restrict__ bstart,
                       const u32* __restrict__ hofs, uint2* __restrict__ recs,
                       int E, int NB, int chunk) {
  __shared__ u32 cur[512];
  int tid = threadIdx.x, blk = blockIdx.x;
  for (int i = tid; i < NB; i += 256)
    cur[i] = bstart[i] + hofs[(size_t)i * NBLK_E + blk];
  __syncthreads();
  int e0 = blk * chunk, e1 = min(E, e0 + chunk);
  for (int e = e0 + tid; e < e1; e += 256) {
    int c = col[e];
    int b = c >> BSH;
    u32 dl = (u32)(c & BMSK);
    u32 pos = atomicAdd(&cur[b], 1u);
    uint2 v; v.x = (u32)row[e] | (dl << 20); v.y = __float_as_uint(ew[e]);
    recs[pos] = v;
  }
}

// Phase B: one block per bucket. LDS count + weighted degree + scan ->
// rowptr, dinv, and final CSR scatter {src, w}.
__global__ void k_build(const uint2* __restrict__ recs, const u32* __restrict__ bstart,
                        u32* __restrict__ rowptr, float* __restrict__ dinv,
                        uint2* __restrict__ csr, int N) {
  __shared__ u32 scnt[256];
  __shared__ float sdeg[256];
  __shared__ u32 cur[256];
  __shared__ u32 s[256];
  int b = blockIdx.x, t = threadIdx.x;
  scnt[t] = 0; sdeg[t] = 0.f;
  __syncthreads();
  u32 r0 = bstart[b], r1 = bstart[b + 1];
  for (u32 e = r0 + t; e < r1; e += 256) {
    uint2 v = recs[e];
    u32 dl = v.x >> 20;
    atomicAdd(&scnt[dl], 1u);
    atomicAdd(&sdeg[dl], __uint_as_float(v.y));
  }
  __syncthreads();
  u32 c = scnt[t];
  s[t] = c; __syncthreads();
  for (int off = 1; off < 256; off <<= 1) {
    u32 x = (t >= off) ? s[t - off] : 0u;
    __syncthreads(); s[t] += x; __syncthreads();
  }
  u32 base = r0 + s[t] - c;
  int node = (b << BSH) + t;
  if (node < N) {
    rowptr[node] = base;
    dinv[node] = rsqrtf(sdeg[t] + 1.0f);   // +1 = self-loop weight
  }
  cur[t] = base;
  __syncthreads();
  for (u32 e = r0 + t; e < r1; e += 256) {
    uint2 v = recs[e];
    u32 dl = v.x >> 20;
    u32 slot = atomicAdd(&cur[dl], 1u);
    uint2 o; o.x = v.x & 0xFFFFFu; o.y = v.y;
    csr[slot] = o;
  }
}

// ht1 = x @ W1  (100000x128 @ 128x16). W1 staged in LDS, broadcast reads.
__global__ void k_gemm1(const float* __restrict__ x, const float* __restrict__ W1,
                        float* __restrict__ ht1, int n) {
  __shared__ float sw[2048];
  for (int i = threadIdx.x; i < 2048; i += blockDim.x) sw[i] = W1[i];
  __syncthreads();
  int node = blockIdx.x * blockDim.x + threadIdx.x;
  if (node >= n) return;
  const float4* xr = (const float4*)(x + (size_t)node * 128);
  float acc[16];
  #pragma unroll
  for (int j = 0; j < 16; j++) acc[j] = 0.f;
  #pragma unroll 4
  for (int k4 = 0; k4 < 32; k4++) {
    float4 xv = xr[k4];
    const float* wb = &sw[k4 * 64];
    #pragma unroll
    for (int j = 0; j < 16; j++) acc[j] += xv.x * wb[j];
    #pragma unroll
    for (int j = 0; j < 16; j++) acc[j] += xv.y * wb[16 + j];
    #pragma unroll
    for (int j = 0; j < 16; j++) acc[j] += xv.z * wb[32 + j];
    #pragma unroll
    for (int j = 0; j < 16; j++) acc[j] += xv.w * wb[48 + j];
  }
  float4* o = (float4*)(ht1 + (size_t)node * 16);
  o[0] = make_float4(acc[0], acc[1], acc[2], acc[3]);
  o[1] = make_float4(acc[4], acc[5], acc[6], acc[7]);
  o[2] = make_float4(acc[8], acc[9], acc[10], acc[11]);
  o[3] = make_float4(acc[12], acc[13], acc[14], acc[15]);
}

// Edge-sum with 8x unrolled, independent load chains.
__device__ __forceinline__ float edge_sum(const float* __restrict__ ht,
                                          const uint2* __restrict__ csr,
                                          const float* __restrict__ dinv,
                                          u32 e0, u32 e1, int j) {
  float acc = 0.f;
  u32 e = e0;
  for (; e + 8 <= e1; e += 8) {
    uint2 v[8];
    #pragma unroll
    for (int t = 0; t < 8; t++) v[t] = csr[e + t];
    float h[8];
    #pragma unroll
    for (int t = 0; t < 8; t++) h[t] = ht[(size_t)v[t].x * 16 + j];
    float nw[8];
    #pragma unroll
    for (int t = 0; t < 8; t++) nw[t] = dinv[v[t].x] * __uint_as_float(v[t].y);
    #pragma unroll
    for (int t = 0; t < 8; t++) acc += nw[t] * h[t];
  }
  for (; e < e1; e++) {
    uint2 v = csr[e];
    acc += dinv[v.x] * __uint_as_float(v.y) * ht[(size_t)v.x * 16 + j];
  }
  return acc;
}

// Conv1 aggregation + bias + relu, fused with @W2 via LDS.
__global__ void k_agg1(const float* __restrict__ ht1, const u32* __restrict__ rowptr,
                       const uint2* __restrict__ csr, const float* __restrict__ dinv,
                       const float* __restrict__ b1, const float* __restrict__ W2,
                       float* __restrict__ ht2, int n) {
  __shared__ float sw2[256];
  __shared__ float sr[16][17];
  int tid = threadIdx.x;
  sw2[tid] = W2[tid];
  int g = tid >> 4, j = tid & 15;
  int node = blockIdx.x * 16 + g;
  float acc = 0.f;
  if (node < n) {
    float di = dinv[node];
    u32 e0 = rowptr[node], e1 = rowptr[node + 1];
    acc = edge_sum(ht1, csr, dinv, e0, e1, j);
    acc = di * (acc + di * ht1[(size_t)node * 16 + j]) + b1[j];
    acc = fmaxf(acc, 0.f);
  }
  sr[g][j] = acc;
  __syncthreads();
  if (node < n) {
    float s = 0.f;
    #pragma unroll
    for (int k = 0; k < 16; k++) s += sr[g][k] * sw2[k * 16 + j];
    ht2[(size_t)node * 16 + j] = s;
  }
}

// Conv2 aggregation + bias, fused with mean-pool partial sums.
__global__ void k_agg2(const float* __restrict__ ht2, const u32* __restrict__ rowptr,
                       const uint2* __restrict__ csr, const float* __restrict__ dinv,
                       const float* __restrict__ b2, const int* __restrict__ batch,
                       float* __restrict__ pooled, int n) {
  __shared__ float sr[16][17];
  __shared__ int sbid[16];
  int tid = threadIdx.x;
  int g = tid >> 4, j = tid & 15;
  int node = blockIdx.x * 16 + g;
  float acc = 0.f;
  int myb = -1;
  if (node < n) {
    float di = dinv[node];
    u32 e0 = rowptr[node], e1 = rowptr[node + 1];
    acc = edge_sum(ht2, csr, dinv, e0, e1, j);
    acc = di * (acc + di * ht2[(size_t)node * 16 + j]) + b2[j];
    myb = batch[node];
  }
  sr[g][j] = acc;
  if (j == 0) sbid[g] = myb;
  __syncthreads();
  if (node < n) {
    bool head = (g == 0) || (sbid[g - 1] != myb);
    if (head) {
      float s = sr[g][j];
      for (int t = g + 1; t < 16 && sbid[t] == myb; t++) s += sr[t][j];
      unsafeAtomicAdd(&pooled[(size_t)myb * 16 + j], s);
    }
  }
}

// Mean + FC. Graph sizes via binary search on sorted batch.
__global__ void k_final(const float* __restrict__ pooled, const int* __restrict__ batch,
                        const float* __restrict__ fcW, const float* __restrict__ fcb,
                        float* __restrict__ out, int n, int G) {
  int g = blockIdx.x * blockDim.x + threadIdx.x;
  if (g >= G) return;
  int lo = 0, hi = n;
  while (lo < hi) { int m = (lo + hi) >> 1; if (batch[m] < g) lo = m + 1; else hi = m; }
  int lo2 = lo, hi2 = n;
  while (lo2 < hi2) { int m = (lo2 + hi2) >> 1; if (batch[m] < g + 1) lo2 = m + 1; else hi2 = m; }
  float c = (float)(lo2 - lo);
  float inv = 1.0f / fmaxf(c, 1.0f);
  float s = 0.f;
  #pragma unroll
  for (int j = 0; j < 16; j++) s += pooled[g * 16 + j] * fcW[j];
  out[g] = s * inv + fcb[0];
}

extern "C" void kernel_launch(void* const* d_in, const int* in_sizes, int n_in,
                              void* d_out, int out_size, void* d_ws, size_t ws_size,
                              hipStream_t stream) {
  const float* x    = (const float*)d_in[0];
  const int*   ei   = (const int*)d_in[1];
  const float* ew   = (const float*)d_in[2];
  const int*   batch= (const int*)d_in[3];
  const float* W1   = (const float*)d_in[4];
  const float* b1   = (const float*)d_in[5];
  const float* W2   = (const float*)d_in[6];
  const float* b2   = (const float*)d_in[7];
  const float* fcW  = (const float*)d_in[8];
  const float* fcb  = (const float*)d_in[9];
  float* out = (float*)d_out;

  int N = in_sizes[3];
  int E = in_sizes[2];
  int G = out_size;
  const int* row = ei;     // edge_index[0] = source
  const int* col = ei + E; // edge_index[1] = target

  int NB = (N + 255) >> BSH;          // buckets of 256 nodes
  int chunk = (E + NBLK_E - 1) / NBLK_E;

  char* w = (char*)d_ws;
  size_t off = 0;
  auto alloc = [&](size_t bytes) -> char* { char* p = w + off; off = al16(off + bytes); return p; };
  u32*   hist   = (u32*)  alloc((size_t)NB * NBLK_E * 4);
  u32*   hofs   = (u32*)  alloc((size_t)NB * NBLK_E * 4);
  u32*   totals = (u32*)  alloc((size_t)NB * 4);
  u32*   bstart = (u32*)  alloc(((size_t)NB + 1) * 4);
  u32*   rowptr = (u32*)  alloc(((size_t)N + 1) * 4);
  float* dinv   = (float*)alloc((size_t)N * 4);
  uint2* recs   = (uint2*)alloc((size_t)E * 8);
  uint2* csr    = (uint2*)alloc((size_t)E * 8);
  float* pooled = (float*)alloc((size_t)G * 16 * 4);
  // recs is dead after k_build: alias ht1/ht2 into it (gemm1 runs later).
  float* ht1 = (float*)recs;
  float* ht2 = (float*)((char*)recs + (size_t)N * 16 * 4);
  (void)ws_size; (void)n_in;

  hipMemsetAsync(pooled, 0, (size_t)G * 16 * 4, stream);

  int nb = (N + 255) / 256;
  int ab = (N + 15) / 16;
  int gb = (G + 255) / 256;

  k_hist <<<NBLK_E, 256, 0, stream>>>(col, hist, E, NB, chunk);
  k_cscan<<<NB, 256, 0, stream>>>(hist, hofs, totals);
  k_bscan<<<1, 512, 0, stream>>>(totals, bstart, rowptr, NB, N, E);
  k_part <<<NBLK_E, 256, 0, stream>>>(row, col, ew, bstart, hofs, recs, E, NB, chunk);
  k_build<<<NB, 256, 0, stream>>>(recs, bstart, rowptr, dinv, csr, N);
  k_gemm1<<<nb, 256, 0, stream>>>(x, W1, ht1, N);
  k_agg1 <<<ab, 256, 0, stream>>>(ht1, rowptr, csr, dinv, b1, W2, ht2, N);
  k_agg2 <<<ab, 256, 0, stream>>>(ht2, rowptr, csr, dinv, b2, batch, pooled, N);
  k_final<<<gb, 256, 0, stream>>>(pooled, batch, fcW, fcb, out, N, G);
}

// Round 5
// 256.778 us; speedup vs baseline: 3.2707x; 1.0798x over previous
//
#include <hip/hip_runtime.h>
#include <hip/hip_fp16.h>

typedef unsigned int u32;

static inline size_t al16(size_t x){ return (x + 15) & ~(size_t)15; }

#define NBLK_E 256          // blocks for edge-partition phases (hist/part)
#define BSH 8               // 256 nodes per bucket
#define BMSK 255

// Phase A1: per-block LDS histogram of dst buckets. hist layout [bucket*NBLK_E + blk].
__global__ void k_hist(const int* __restrict__ col, u32* __restrict__ hist,
                       int E, int NB, int chunk) {
  __shared__ u32 h[512];
  int tid = threadIdx.x, blk = blockIdx.x;
  for (int i = tid; i < 512; i += 256) h[i] = 0;
  __syncthreads();
  int e0 = blk * chunk, e1 = min(E, e0 + chunk);
  for (int e = e0 + tid; e < e1; e += 256) atomicAdd(&h[col[e] >> BSH], 1u);
  __syncthreads();
  for (int i = tid; i < NB; i += 256) hist[(size_t)i * NBLK_E + blk] = h[i];
}

// Phase A2a: per-bucket exclusive scan over blocks -> hofs; bucket totals.
__global__ void k_cscan(const u32* __restrict__ hist, u32* __restrict__ hofs,
                        u32* __restrict__ totals) {
  __shared__ u32 s[256];
  int i = blockIdx.x, t = threadIdx.x;
  u32 v = hist[(size_t)i * NBLK_E + t];
  s[t] = v; __syncthreads();
  for (int off = 1; off < 256; off <<= 1) {
    u32 x = (t >= off) ? s[t - off] : 0u;
    __syncthreads(); s[t] += x; __syncthreads();
  }
  hofs[(size_t)i * NBLK_E + t] = s[t] - v;
  if (t == 255) totals[i] = s[255];
}

// Phase A2b: scan bucket totals -> bstart (edge-region & CSR base per bucket).
__global__ void k_bscan(const u32* __restrict__ totals, u32* __restrict__ bstart,
                        u32* __restrict__ rowptr, int NB, int N, int E) {
  __shared__ u32 s[512];
  int t = threadIdx.x;
  u32 v = (t < NB) ? totals[t] : 0u;
  s[t] = v; __syncthreads();
  for (int off = 1; off < 512; off <<= 1) {
    u32 x = (t >= off) ? s[t - off] : 0u;
    __syncthreads(); s[t] += x; __syncthreads();
  }
  if (t < NB) bstart[t] = s[t] - v;
  if (t == 0) { bstart[NB] = (u32)E; rowptr[N] = (u32)E; }
}

// Phase A3: scatter edges into bucket-contiguous records. No global atomics.
__global__ void k_part(const int* __restrict__ row, const int* __restrict__ col,
                       const float* __restrict__ ew, const u32* __restrict__ bstart,
                       const u32* __restrict__ hofs, uint2* __restrict__ recs,
                       int E, int NB, int chunk) {
  __shared__ u32 cur[512];
  int tid = threadIdx.x, blk = blockIdx.x;
  for (int i = tid; i < NB; i += 256)
    cur[i] = bstart[i] + hofs[(size_t)i * NBLK_E + blk];
  __syncthreads();
  int e0 = blk * chunk, e1 = min(E, e0 + chunk);
  for (int e = e0 + tid; e < e1; e += 256) {
    int c = col[e];
    int b = c >> BSH;
    u32 dl = (u32)(c & BMSK);
    u32 pos = atomicAdd(&cur[b], 1u);
    uint2 v; v.x = (u32)row[e] | (dl << 20); v.y = __float_as_uint(ew[e]);
    recs[pos] = v;
  }
}

// Phase B: one block per bucket -> rowptr, dinv, final CSR {src, w}.
__global__ void k_build(const uint2* __restrict__ recs, const u32* __restrict__ bstart,
                        u32* __restrict__ rowptr, float* __restrict__ dinv,
                        uint2* __restrict__ csr, int N) {
  __shared__ u32 scnt[256];
  __shared__ float sdeg[256];
  __shared__ u32 cur[256];
  __shared__ u32 s[256];
  int b = blockIdx.x, t = threadIdx.x;
  scnt[t] = 0; sdeg[t] = 0.f;
  __syncthreads();
  u32 r0 = bstart[b], r1 = bstart[b + 1];
  for (u32 e = r0 + t; e < r1; e += 256) {
    uint2 v = recs[e];
    u32 dl = v.x >> 20;
    atomicAdd(&scnt[dl], 1u);
    atomicAdd(&sdeg[dl], __uint_as_float(v.y));
  }
  __syncthreads();
  u32 c = scnt[t];
  s[t] = c; __syncthreads();
  for (int off = 1; off < 256; off <<= 1) {
    u32 x = (t >= off) ? s[t - off] : 0u;
    __syncthreads(); s[t] += x; __syncthreads();
  }
  u32 base = r0 + s[t] - c;
  int node = (b << BSH) + t;
  if (node < N) {
    rowptr[node] = base;
    dinv[node] = rsqrtf(sdeg[t] + 1.0f);   // +1 = self-loop weight
  }
  cur[t] = base;
  __syncthreads();
  for (u32 e = r0 + t; e < r1; e += 256) {
    uint2 v = recs[e];
    u32 dl = v.x >> 20;
    u32 slot = atomicAdd(&cur[dl], 1u);
    uint2 o; o.x = v.x & 0xFFFFFu; o.y = v.y;
    csr[slot] = o;
  }
}

// ht1 = x @ W1, output fp16 (table becomes L2-resident: 3.2MB < 4MB/XCD).
__global__ void k_gemm1(const float* __restrict__ x, const float* __restrict__ W1,
                        __half* __restrict__ ht1, int n) {
  __shared__ float sw[2048];
  for (int i = threadIdx.x; i < 2048; i += blockDim.x) sw[i] = W1[i];
  __syncthreads();
  int node = blockIdx.x * blockDim.x + threadIdx.x;
  if (node >= n) return;
  const float4* xr = (const float4*)(x + (size_t)node * 128);
  float acc[16];
  #pragma unroll
  for (int j = 0; j < 16; j++) acc[j] = 0.f;
  #pragma unroll 4
  for (int k4 = 0; k4 < 32; k4++) {
    float4 xv = xr[k4];
    const float* wb = &sw[k4 * 64];
    #pragma unroll
    for (int j = 0; j < 16; j++) acc[j] += xv.x * wb[j];
    #pragma unroll
    for (int j = 0; j < 16; j++) acc[j] += xv.y * wb[16 + j];
    #pragma unroll
    for (int j = 0; j < 16; j++) acc[j] += xv.z * wb[32 + j];
    #pragma unroll
    for (int j = 0; j < 16; j++) acc[j] += xv.w * wb[48 + j];
  }
  u32 o[8];
  #pragma unroll
  for (int p = 0; p < 8; p++) {
    u32 lo = (u32)__half_as_ushort(__float2half(acc[2 * p]));
    u32 hi = (u32)__half_as_ushort(__float2half(acc[2 * p + 1]));
    o[p] = lo | (hi << 16);
  }
  uint4* dst = (uint4*)(ht1 + (size_t)node * 16);
  dst[0] = make_uint4(o[0], o[1], o[2], o[3]);
  dst[1] = make_uint4(o[4], o[5], o[6], o[7]);
}

// Edge-sum over fp16 table, 8x unrolled independent load chains.
__device__ __forceinline__ float edge_sum(const __half* __restrict__ ht,
                                          const uint2* __restrict__ csr,
                                          const float* __restrict__ dinv,
                                          u32 e0, u32 e1, int j) {
  float acc = 0.f;
  u32 e = e0;
  for (; e + 8 <= e1; e += 8) {
    uint2 v[8];
    #pragma unroll
    for (int t = 0; t < 8; t++) v[t] = csr[e + t];
    float h[8];
    #pragma unroll
    for (int t = 0; t < 8; t++) h[t] = __half2float(ht[(size_t)v[t].x * 16 + j]);
    float nw[8];
    #pragma unroll
    for (int t = 0; t < 8; t++) nw[t] = dinv[v[t].x] * __uint_as_float(v[t].y);
    #pragma unroll
    for (int t = 0; t < 8; t++) acc += nw[t] * h[t];
  }
  for (; e < e1; e++) {
    uint2 v = csr[e];
    acc += dinv[v.x] * __uint_as_float(v.y) * __half2float(ht[(size_t)v.x * 16 + j]);
  }
  return acc;
}

// Conv1 aggregation + bias + relu, fused with @W2 via LDS. fp16 in/out, fp32 math.
__global__ void k_agg1(const __half* __restrict__ ht1, const u32* __restrict__ rowptr,
                       const uint2* __restrict__ csr, const float* __restrict__ dinv,
                       const float* __restrict__ b1, const float* __restrict__ W2,
                       __half* __restrict__ ht2, int n) {
  __shared__ float sw2[256];
  __shared__ float sr[16][17];
  int tid = threadIdx.x;
  sw2[tid] = W2[tid];
  int g = tid >> 4, j = tid & 15;
  int node = blockIdx.x * 16 + g;
  float acc = 0.f;
  if (node < n) {
    float di = dinv[node];
    u32 e0 = rowptr[node], e1 = rowptr[node + 1];
    acc = edge_sum(ht1, csr, dinv, e0, e1, j);
    acc = di * (acc + di * __half2float(ht1[(size_t)node * 16 + j])) + b1[j];
    acc = fmaxf(acc, 0.f);
  }
  sr[g][j] = acc;
  __syncthreads();
  if (node < n) {
    float s = 0.f;
    #pragma unroll
    for (int k = 0; k < 16; k++) s += sr[g][k] * sw2[k * 16 + j];
    ht2[(size_t)node * 16 + j] = __float2half(s);
  }
}

// Conv2 aggregation + bias, fused with mean-pool partial sums.
__global__ void k_agg2(const __half* __restrict__ ht2, const u32* __restrict__ rowptr,
                       const uint2* __restrict__ csr, const float* __restrict__ dinv,
                       const float* __restrict__ b2, const int* __restrict__ batch,
                       float* __restrict__ pooled, int n) {
  __shared__ float sr[16][17];
  __shared__ int sbid[16];
  int tid = threadIdx.x;
  int g = tid >> 4, j = tid & 15;
  int node = blockIdx.x * 16 + g;
  float acc = 0.f;
  int myb = -1;
  if (node < n) {
    float di = dinv[node];
    u32 e0 = rowptr[node], e1 = rowptr[node + 1];
    acc = edge_sum(ht2, csr, dinv, e0, e1, j);
    acc = di * (acc + di * __half2float(ht2[(size_t)node * 16 + j])) + b2[j];
    myb = batch[node];
  }
  sr[g][j] = acc;
  if (j == 0) sbid[g] = myb;
  __syncthreads();
  if (node < n) {
    bool head = (g == 0) || (sbid[g - 1] != myb);
    if (head) {
      float s = sr[g][j];
      for (int t = g + 1; t < 16 && sbid[t] == myb; t++) s += sr[t][j];
      unsafeAtomicAdd(&pooled[(size_t)myb * 16 + j], s);
    }
  }
}

// Mean + FC. Graph sizes via binary search on sorted batch.
__global__ void k_final(const float* __restrict__ pooled, const int* __restrict__ batch,
                        const float* __restrict__ fcW, const float* __restrict__ fcb,
                        float* __restrict__ out, int n, int G) {
  int g = blockIdx.x * blockDim.x + threadIdx.x;
  if (g >= G) return;
  int lo = 0, hi = n;
  while (lo < hi) { int m = (lo + hi) >> 1; if (batch[m] < g) lo = m + 1; else hi = m; }
  int lo2 = lo, hi2 = n;
  while (lo2 < hi2) { int m = (lo2 + hi2) >> 1; if (batch[m] < g + 1) lo2 = m + 1; else hi2 = m; }
  float c = (float)(lo2 - lo);
  float inv = 1.0f / fmaxf(c, 1.0f);
  float s = 0.f;
  #pragma unroll
  for (int j = 0; j < 16; j++) s += pooled[g * 16 + j] * fcW[j];
  out[g] = s * inv + fcb[0];
}

extern "C" void kernel_launch(void* const* d_in, const int* in_sizes, int n_in,
                              void* d_out, int out_size, void* d_ws, size_t ws_size,
                              hipStream_t stream) {
  const float* x    = (const float*)d_in[0];
  const int*   ei   = (const int*)d_in[1];
  const float* ew   = (const float*)d_in[2];
  const int*   batch= (const int*)d_in[3];
  const float* W1   = (const float*)d_in[4];
  const float* b1   = (const float*)d_in[5];
  const float* W2   = (const float*)d_in[6];
  const float* b2   = (const float*)d_in[7];
  const float* fcW  = (const float*)d_in[8];
  const float* fcb  = (const float*)d_in[9];
  float* out = (float*)d_out;

  int N = in_sizes[3];
  int E = in_sizes[2];
  int G = out_size;
  const int* row = ei;     // edge_index[0] = source
  const int* col = ei + E; // edge_index[1] = target

  int NB = (N + 255) >> BSH;          // buckets of 256 nodes
  int chunk = (E + NBLK_E - 1) / NBLK_E;

  char* w = (char*)d_ws;
  size_t off = 0;
  auto alloc = [&](size_t bytes) -> char* { char* p = w + off; off = al16(off + bytes); return p; };
  u32*   hist   = (u32*)  alloc((size_t)NB * NBLK_E * 4);
  u32*   hofs   = (u32*)  alloc((size_t)NB * NBLK_E * 4);
  u32*   totals = (u32*)  alloc((size_t)NB * 4);
  u32*   bstart = (u32*)  alloc(((size_t)NB + 1) * 4);
  u32*   rowptr = (u32*)  alloc(((size_t)N + 1) * 4);
  float* dinv   = (float*)alloc((size_t)N * 4);
  uint2* recs   = (uint2*)alloc((size_t)E * 8);
  uint2* csr    = (uint2*)alloc((size_t)E * 8);
  float* pooled = (float*)alloc((size_t)G * 16 * 4);
  // recs is dead after k_build: alias fp16 ht1/ht2 into it (gemm1 runs later).
  __half* ht1 = (__half*)recs;
  __half* ht2 = (__half*)((char*)recs + (size_t)N * 16 * 2);
  (void)ws_size; (void)n_in;

  hipMemsetAsync(pooled, 0, (size_t)G * 16 * 4, stream);

  int nb = (N + 255) / 256;
  int ab = (N + 15) / 16;
  int gb = (G + 255) / 256;

  k_hist <<<NBLK_E, 256, 0, stream>>>(col, hist, E, NB, chunk);
  k_cscan<<<NB, 256, 0, stream>>>(hist, hofs, totals);
  k_bscan<<<1, 512, 0, stream>>>(totals, bstart, rowptr, NB, N, E);
  k_part <<<NBLK_E, 256, 0, stream>>>(row, col, ew, bstart, hofs, recs, E, NB, chunk);
  k_build<<<NB, 256, 0, stream>>>(recs, bstart, rowptr, dinv, csr, N);
  k_gemm1<<<nb, 256, 0, stream>>>(x, W1, ht1, N);
  k_agg1 <<<ab, 256, 0, stream>>>(ht1, rowptr, csr, dinv, b1, W2, ht2, N);
  k_agg2 <<<ab, 256, 0, stream>>>(ht2, rowptr, csr, dinv, b2, batch, pooled, N);
  k_final<<<gb, 256, 0, stream>>>(pooled, batch, fcW, fcb, out, N, G);
}

// Round 6
// 239.354 us; speedup vs baseline: 3.5088x; 1.0728x over previous
//
#include <hip/hip_runtime.h>
#include <hip/hip_fp16.h>

typedef unsigned int u32;

static inline size_t al16(size_t x){ return (x + 15) & ~(size_t)15; }

#define NPB 128            // nodes per bucket
#define PBSH 7
#define PBMSK 127

// Phase A1: per-block LDS histogram of dst buckets. hist layout [blk][bucket] (contiguous writes).
__global__ void k_hist(const int* __restrict__ col, u32* __restrict__ hist,
                       int E, int NB, int chunk) {
  __shared__ u32 h[1024];
  int tid = threadIdx.x, blk = blockIdx.x;
  for (int i = tid; i < 1024; i += 256) h[i] = 0;
  __syncthreads();
  int e0 = blk * chunk, e1 = min(E, e0 + chunk);
  for (int e = e0 + tid; e < e1; e += 256) atomicAdd(&h[col[e] >> PBSH], 1u);
  __syncthreads();
  for (int i = tid; i < NB; i += 256) hist[(size_t)blk * NB + i] = h[i];
}

// Phase A2a: per-bucket exclusive scan over blocks. Reads hist[blk][i] (strided),
// writes hofs[i][blk] (contiguous).
__global__ void k_cscan(const u32* __restrict__ hist, u32* __restrict__ hofs,
                        u32* __restrict__ totals, int NB, int nblk) {
  __shared__ u32 s[256];
  int i = blockIdx.x, t = threadIdx.x;
  int R = nblk >> 8;               // nblk in {256,512,1024}
  u32 v[4]; u32 tsum = 0;
  for (int r = 0; r < R; r++) { v[r] = hist[(size_t)(t * R + r) * NB + i]; tsum += v[r]; }
  s[t] = tsum; __syncthreads();
  for (int off = 1; off < 256; off <<= 1) {
    u32 x = (t >= off) ? s[t - off] : 0u;
    __syncthreads(); s[t] += x; __syncthreads();
  }
  u32 run = s[t] - tsum;
  u32* hb = &hofs[(size_t)i * nblk + t * R];
  for (int r = 0; r < R; r++) { hb[r] = run; run += v[r]; }
  if (t == 255) totals[i] = s[255];
}

// Phase A2b: scan bucket totals -> bstart.
__global__ void k_bscan(const u32* __restrict__ totals, u32* __restrict__ bstart,
                        u32* __restrict__ rowptr, int NB, int N, int E) {
  __shared__ u32 s[1024];
  int t = threadIdx.x;
  u32 v = (t < NB) ? totals[t] : 0u;
  s[t] = v; __syncthreads();
  for (int off = 1; off < 1024; off <<= 1) {
    u32 x = (t >= off) ? s[t - off] : 0u;
    __syncthreads(); s[t] += x; __syncthreads();
  }
  if (t < NB) bstart[t] = s[t] - v;
  if (t == 0) { bstart[NB] = (u32)E; rowptr[N] = (u32)E; }
}

// Phase A3: scatter edges into bucket-contiguous records. No global atomics.
__global__ void k_part(const int* __restrict__ row, const int* __restrict__ col,
                       const float* __restrict__ ew, const u32* __restrict__ bstart,
                       const u32* __restrict__ hofs, uint2* __restrict__ recs,
                       int E, int NB, int nblk, int chunk) {
  __shared__ u32 cur[1024];
  int tid = threadIdx.x, blk = blockIdx.x;
  for (int i = tid; i < NB; i += 256)
    cur[i] = bstart[i] + hofs[(size_t)i * nblk + blk];
  __syncthreads();
  int e0 = blk * chunk, e1 = min(E, e0 + chunk);
  for (int e = e0 + tid; e < e1; e += 256) {
    int c = col[e];
    int b = c >> PBSH;
    u32 dl = (u32)(c & PBMSK);
    u32 pos = atomicAdd(&cur[b], 1u);
    uint2 v; v.x = (u32)row[e] | (dl << 20); v.y = __float_as_uint(ew[e]);
    recs[pos] = v;
  }
}

// Phase B1: per-bucket degree + rowptr + dinv (no csr write yet).
__global__ void k_build1(const uint2* __restrict__ recs, const u32* __restrict__ bstart,
                         u32* __restrict__ rowptr, float* __restrict__ dinv, int N) {
  __shared__ u32 scnt[NPB];
  __shared__ float sdeg[NPB];
  __shared__ u32 s[NPB];
  int b = blockIdx.x, t = threadIdx.x;
  if (t < NPB) { scnt[t] = 0; sdeg[t] = 0.f; }
  __syncthreads();
  u32 r0 = bstart[b], r1 = bstart[b + 1];
  for (u32 e = r0 + t; e < r1; e += 256) {
    uint2 v = recs[e];
    u32 dl = v.x >> 20;
    atomicAdd(&scnt[dl], 1u);
    atomicAdd(&sdeg[dl], __uint_as_float(v.y));
  }
  __syncthreads();
  if (t < NPB) s[t] = scnt[t];
  __syncthreads();
  for (int off = 1; off < NPB; off <<= 1) {
    u32 x = 0;
    if (t < NPB && t >= off) x = s[t - off];
    __syncthreads();
    if (t < NPB) s[t] += x;
    __syncthreads();
  }
  if (t < NPB) {
    int node = (b << PBSH) + t;
    if (node < N) {
      rowptr[node] = r0 + s[t] - scnt[t];
      dinv[node] = rsqrtf(sdeg[t] + 1.0f);   // +1 = self-loop weight
    }
  }
}

// Phase B2: scatter final CSR with pre-scaled weight dinv[src]*w (dinv complete).
__global__ void k_build2(const uint2* __restrict__ recs, const u32* __restrict__ bstart,
                         const u32* __restrict__ rowptr, const float* __restrict__ dinv,
                         uint2* __restrict__ csr, int N) {
  __shared__ u32 cur[NPB];
  int b = blockIdx.x, t = threadIdx.x;
  if (t < NPB) {
    int node = (b << PBSH) + t;
    cur[t] = (node < N) ? rowptr[node] : 0u;
  }
  __syncthreads();
  u32 r0 = bstart[b], r1 = bstart[b + 1];
  for (u32 e = r0 + t; e < r1; e += 256) {
    uint2 v = recs[e];
    u32 dl = v.x >> 20;
    u32 src = v.x & 0xFFFFFu;
    u32 slot = atomicAdd(&cur[dl], 1u);
    uint2 o; o.x = src; o.y = __float_as_uint(dinv[src] * __uint_as_float(v.y));
    csr[slot] = o;
  }
}

// ht1 = x @ W1, output fp16 (table L2-resident: 3.2MB).
__global__ void k_gemm1(const float* __restrict__ x, const float* __restrict__ W1,
                        __half* __restrict__ ht1, int n) {
  __shared__ float sw[2048];
  for (int i = threadIdx.x; i < 2048; i += blockDim.x) sw[i] = W1[i];
  __syncthreads();
  int node = blockIdx.x * blockDim.x + threadIdx.x;
  if (node >= n) return;
  const float4* xr = (const float4*)(x + (size_t)node * 128);
  float acc[16];
  #pragma unroll
  for (int j = 0; j < 16; j++) acc[j] = 0.f;
  #pragma unroll 4
  for (int k4 = 0; k4 < 32; k4++) {
    float4 xv = xr[k4];
    const float* wb = &sw[k4 * 64];
    #pragma unroll
    for (int j = 0; j < 16; j++) acc[j] += xv.x * wb[j];
    #pragma unroll
    for (int j = 0; j < 16; j++) acc[j] += xv.y * wb[16 + j];
    #pragma unroll
    for (int j = 0; j < 16; j++) acc[j] += xv.z * wb[32 + j];
    #pragma unroll
    for (int j = 0; j < 16; j++) acc[j] += xv.w * wb[48 + j];
  }
  u32 o[8];
  #pragma unroll
  for (int p = 0; p < 8; p++) {
    u32 lo = (u32)__half_as_ushort(__float2half(acc[2 * p]));
    u32 hi = (u32)__half_as_ushort(__float2half(acc[2 * p + 1]));
    o[p] = lo | (hi << 16);
  }
  uint4* dst = (uint4*)(ht1 + (size_t)node * 16);
  dst[0] = make_uint4(o[0], o[1], o[2], o[3]);
  dst[1] = make_uint4(o[4], o[5], o[6], o[7]);
}

// Per-edge core for 4-lane-per-node layout: lane s owns channels 4s..4s+3.
// Weight already pre-scaled by dinv[src]; accumulate 4 fp32 channels.
__device__ __forceinline__ void edge_sum4(const __half* __restrict__ ht,
                                          const uint2* __restrict__ csr,
                                          u32 e0, u32 e1, int s,
                                          float& a0, float& a1, float& a2, float& a3) {
  u32 e = e0;
  for (; e + 8 <= e1; e += 8) {
    uint2 v[8];
    #pragma unroll
    for (int t = 0; t < 8; t++) v[t] = csr[e + t];
    uint2 h[8];
    #pragma unroll
    for (int t = 0; t < 8; t++)
      h[t] = *(const uint2*)(ht + (size_t)v[t].x * 16 + s * 4);
    #pragma unroll
    for (int t = 0; t < 8; t++) {
      float w = __uint_as_float(v[t].y);
      float2 lo = __half22float2(*(__half2*)&h[t].x);
      float2 hi = __half22float2(*(__half2*)&h[t].y);
      a0 += w * lo.x; a1 += w * lo.y; a2 += w * hi.x; a3 += w * hi.y;
    }
  }
  for (; e < e1; e++) {
    uint2 v = csr[e];
    uint2 h = *(const uint2*)(ht + (size_t)v.x * 16 + s * 4);
    float w = __uint_as_float(v.y);
    float2 lo = __half22float2(*(__half2*)&h.x);
    float2 hi = __half22float2(*(__half2*)&h.y);
    a0 += w * lo.x; a1 += w * lo.y; a2 += w * hi.x; a3 += w * hi.y;
  }
}

// Conv1 agg + bias + relu, fused @W2. 4 lanes/node, 64 nodes/block.
__global__ void k_agg1(const __half* __restrict__ ht1, const u32* __restrict__ rowptr,
                       const uint2* __restrict__ csr, const float* __restrict__ dinv,
                       const float* __restrict__ b1, const float* __restrict__ W2,
                       __half* __restrict__ ht2, int n) {
  __shared__ float sw2[256];
  __shared__ float sr[64][20];
  int tid = threadIdx.x;
  sw2[tid] = W2[tid];
  int g = tid >> 2, s = tid & 3;
  int node = blockIdx.x * 64 + g;
  float a0 = 0.f, a1 = 0.f, a2 = 0.f, a3 = 0.f;
  if (node < n) {
    u32 e0 = rowptr[node], e1 = rowptr[node + 1];
    edge_sum4(ht1, csr, e0, e1, s, a0, a1, a2, a3);
    float di = dinv[node];
    uint2 hs = *(const uint2*)(ht1 + (size_t)node * 16 + s * 4);
    float2 slo = __half22float2(*(__half2*)&hs.x);
    float2 shi = __half22float2(*(__half2*)&hs.y);
    a0 = fmaxf(di * (a0 + di * slo.x) + b1[4 * s + 0], 0.f);
    a1 = fmaxf(di * (a1 + di * slo.y) + b1[4 * s + 1], 0.f);
    a2 = fmaxf(di * (a2 + di * shi.x) + b1[4 * s + 2], 0.f);
    a3 = fmaxf(di * (a3 + di * shi.y) + b1[4 * s + 3], 0.f);
  }
  *(float4*)&sr[g][4 * s] = make_float4(a0, a1, a2, a3);
  __syncthreads();
  if (node < n) {
    float o0 = 0.f, o1 = 0.f, o2 = 0.f, o3 = 0.f;
    #pragma unroll
    for (int k = 0; k < 16; k++) {
      float hk = sr[g][k];
      const float* wr = &sw2[k * 16 + 4 * s];
      o0 += hk * wr[0]; o1 += hk * wr[1]; o2 += hk * wr[2]; o3 += hk * wr[3];
    }
    __half2 p0 = __floats2half2_rn(o0, o1), p1 = __floats2half2_rn(o2, o3);
    uint2 st; st.x = *(u32*)&p0; st.y = *(u32*)&p1;
    *(uint2*)(ht2 + (size_t)node * 16 + 4 * s) = st;
  }
}

// Conv2 agg + bias, fused mean-pool partial sums (segmented LDS reduce).
__global__ void k_agg2(const __half* __restrict__ ht2, const u32* __restrict__ rowptr,
                       const uint2* __restrict__ csr, const float* __restrict__ dinv,
                       const float* __restrict__ b2, const int* __restrict__ batch,
                       float* __restrict__ pooled, int n) {
  __shared__ float sr[64][20];
  __shared__ int sbid[64];
  int tid = threadIdx.x;
  int g = tid >> 2, s = tid & 3;
  int node = blockIdx.x * 64 + g;
  float a0 = 0.f, a1 = 0.f, a2 = 0.f, a3 = 0.f;
  int myb = -1;
  if (node < n) {
    u32 e0 = rowptr[node], e1 = rowptr[node + 1];
    edge_sum4(ht2, csr, e0, e1, s, a0, a1, a2, a3);
    float di = dinv[node];
    uint2 hs = *(const uint2*)(ht2 + (size_t)node * 16 + s * 4);
    float2 slo = __half22float2(*(__half2*)&hs.x);
    float2 shi = __half22float2(*(__half2*)&hs.y);
    a0 = di * (a0 + di * slo.x) + b2[4 * s + 0];
    a1 = di * (a1 + di * slo.y) + b2[4 * s + 1];
    a2 = di * (a2 + di * shi.x) + b2[4 * s + 2];
    a3 = di * (a3 + di * shi.y) + b2[4 * s + 3];
    myb = batch[node];
  }
  *(float4*)&sr[g][4 * s] = make_float4(a0, a1, a2, a3);
  if (s == 0) sbid[g] = myb;
  __syncthreads();
  if (node < n) {
    bool head = (g == 0) || (sbid[g - 1] != myb);
    if (head) {
      float s0 = sr[g][4 * s + 0], s1 = sr[g][4 * s + 1];
      float s2 = sr[g][4 * s + 2], s3 = sr[g][4 * s + 3];
      for (int t = g + 1; t < 64 && sbid[t] == myb; t++) {
        s0 += sr[t][4 * s + 0]; s1 += sr[t][4 * s + 1];
        s2 += sr[t][4 * s + 2]; s3 += sr[t][4 * s + 3];
      }
      float* pb = &pooled[(size_t)myb * 16 + 4 * s];
      unsafeAtomicAdd(pb + 0, s0);
      unsafeAtomicAdd(pb + 1, s1);
      unsafeAtomicAdd(pb + 2, s2);
      unsafeAtomicAdd(pb + 3, s3);
    }
  }
}

// Mean + FC. Graph sizes via binary search on sorted batch.
__global__ void k_final(const float* __restrict__ pooled, const int* __restrict__ batch,
                        const float* __restrict__ fcW, const float* __restrict__ fcb,
                        float* __restrict__ out, int n, int G) {
  int g = blockIdx.x * blockDim.x + threadIdx.x;
  if (g >= G) return;
  int lo = 0, hi = n;
  while (lo < hi) { int m = (lo + hi) >> 1; if (batch[m] < g) lo = m + 1; else hi = m; }
  int lo2 = lo, hi2 = n;
  while (lo2 < hi2) { int m = (lo2 + hi2) >> 1; if (batch[m] < g + 1) lo2 = m + 1; else hi2 = m; }
  float c = (float)(lo2 - lo);
  float inv = 1.0f / fmaxf(c, 1.0f);
  float s = 0.f;
  #pragma unroll
  for (int j = 0; j < 16; j++) s += pooled[g * 16 + j] * fcW[j];
  out[g] = s * inv + fcb[0];
}

extern "C" void kernel_launch(void* const* d_in, const int* in_sizes, int n_in,
                              void* d_out, int out_size, void* d_ws, size_t ws_size,
                              hipStream_t stream) {
  const float* x    = (const float*)d_in[0];
  const int*   ei   = (const int*)d_in[1];
  const float* ew   = (const float*)d_in[2];
  const int*   batch= (const int*)d_in[3];
  const float* W1   = (const float*)d_in[4];
  const float* b1   = (const float*)d_in[5];
  const float* W2   = (const float*)d_in[6];
  const float* b2   = (const float*)d_in[7];
  const float* fcW  = (const float*)d_in[8];
  const float* fcb  = (const float*)d_in[9];
  float* out = (float*)d_out;

  int N = in_sizes[3];
  int E = in_sizes[2];
  int G = out_size;
  const int* row = ei;     // edge_index[0] = source
  const int* col = ei + E; // edge_index[1] = target

  int NB = (N + NPB - 1) >> PBSH;

  // Pick nblk (partition parallelism) to fit ws.
  size_t fixed = al16((size_t)NB * 4) + al16(((size_t)NB + 1) * 4) +
                 al16(((size_t)N + 1) * 4) + al16((size_t)N * 4) +
                 al16((size_t)E * 8) * 2 + al16((size_t)G * 16 * 4);
  int nblk = 1024;
  while (nblk > 256 && fixed + 2 * al16((size_t)NB * nblk * 4) > ws_size) nblk >>= 1;
  int chunk = (E + nblk - 1) / nblk;

  char* w = (char*)d_ws;
  size_t off = 0;
  auto alloc = [&](size_t bytes) -> char* { char* p = w + off; off = al16(off + bytes); return p; };
  u32*   hist   = (u32*)  alloc((size_t)NB * nblk * 4);
  u32*   hofs   = (u32*)  alloc((size_t)NB * nblk * 4);
  u32*   totals = (u32*)  alloc((size_t)NB * 4);
  u32*   bstart = (u32*)  alloc(((size_t)NB + 1) * 4);
  u32*   rowptr = (u32*)  alloc(((size_t)N + 1) * 4);
  float* dinv   = (float*)alloc((size_t)N * 4);
  uint2* recs   = (uint2*)alloc((size_t)E * 8);
  uint2* csr    = (uint2*)alloc((size_t)E * 8);
  float* pooled = (float*)alloc((size_t)G * 16 * 4);
  // recs dead after k_build2: alias fp16 ht1/ht2 (gemm1 runs later).
  __half* ht1 = (__half*)recs;
  __half* ht2 = (__half*)((char*)recs + (size_t)N * 16 * 2);
  (void)n_in;

  hipMemsetAsync(pooled, 0, (size_t)G * 16 * 4, stream);

  int nb = (N + 255) / 256;
  int ab = (N + 63) / 64;
  int gb = (G + 255) / 256;

  k_hist  <<<nblk, 256, 0, stream>>>(col, hist, E, NB, chunk);
  k_cscan <<<NB, 256, 0, stream>>>(hist, hofs, totals, NB, nblk);
  k_bscan <<<1, 1024, 0, stream>>>(totals, bstart, rowptr, NB, N, E);
  k_part  <<<nblk, 256, 0, stream>>>(row, col, ew, bstart, hofs, recs, E, NB, nblk, chunk);
  k_build1<<<NB, 256, 0, stream>>>(recs, bstart, rowptr, dinv, N);
  k_build2<<<NB, 256, 0, stream>>>(recs, bstart, rowptr, dinv, csr, N);
  k_gemm1 <<<nb, 256, 0, stream>>>(x, W1, ht1, N);
  k_agg1  <<<ab, 256, 0, stream>>>(ht1, rowptr, csr, dinv, b1, W2, ht2, N);
  k_agg2  <<<ab, 256, 0, stream>>>(ht2, rowptr, csr, dinv, b2, batch, pooled, N);
  k_final <<<gb, 256, 0, stream>>>(pooled, batch, fcW, fcb, out, N, G);
}